// Round 1
// baseline (1006.221 us; speedup 1.0000x reference)
//
#include <hip/hip_runtime.h>
#include <hip/hip_bf16.h>
#include <cstdint>

// ============================================================================
// IsoNSProject: H = e0 e0^T + polar(P H_raw P) restricted to 1-perp subspace.
// Never materializes U: NS iteration conjugated into n-dim space via
//   B0 = P H P / s,  B <- (1.5 I - 0.5 B B^T) B,  H = B_final + 1/n.
// All matmuls are bf16 MFMA (16x16x32), fp32 accumulate, C = A * B^T form
// (both operands staged [row][k], which is what global_load_lds allows).
// Spectral norm via repeated squaring: s = ||(X X^T)^8||_F^(1/32) * 1.02
// (overestimate factor <= n^(1/32) = 1.27; 8 NS steps converge from
// sigma_min ~ 0.5 to < 1e-6, far below the bf16 noise floor ~4e-3).
// ============================================================================

#define N 2048
#define NSTEPS 8

typedef __bf16 bf16x8 __attribute__((ext_vector_type(8)));
typedef float  f32x4  __attribute__((ext_vector_type(4)));

typedef const void __attribute__((address_space(1))) gvoid;
typedef void __attribute__((address_space(3)))       svoid;

__device__ __forceinline__ void load16_lds(const void* g, void* l) {
    // 16B direct global->LDS DMA; LDS dest = wave-uniform base + lane*16.
    __builtin_amdgcn_global_load_lds((gvoid*)(uintptr_t)g,
                                     (svoid*)(uint32_t)(uintptr_t)l, 16, 0, 0);
}

__device__ __forceinline__ unsigned short f2bf(float x) {
    __hip_bfloat16 h = __float2bfloat16(x);   // RNE
    return *reinterpret_cast<unsigned short*>(&h);
}

// ---------------------------------------------------------------------------
// GEMM: C[i][j] = sum_k A[i][k] * B[j][k]   (i.e. C = A * B^T), 2048^3.
// 128x128 block tile, BK=32, 256 threads (4 waves, 2x2 of 64x64 wave tiles),
// double-buffered LDS (critical: grid = 256 blocks = 1 block/CU at N=2048,
// so there are no sibling waves to hide the staging latency).
// MODE 0: Cb = bf16(acc)
// MODE 1: Cb = bf16(1.5*I - 0.5*acc)          (the NS "M" matrix)
// MODE 2: Cf = acc (fp32) + row/col/total sum atomics (for re-centering)
// MODE 3: atomicAdd(tot, sum(acc^2))  (Frobenius^2, no store)
// ---------------------------------------------------------------------------
template<int MODE>
__global__ __launch_bounds__(256)
void gemm_bt(const unsigned short* __restrict__ A, const unsigned short* __restrict__ B,
             unsigned short* __restrict__ Cb, float* __restrict__ Cf,
             float* __restrict__ rowsum, float* __restrict__ colsum,
             float* __restrict__ tot, const float* __restrict__ scale_p)
{
    __shared__ __align__(16) unsigned short As[2][128 * 32];
    __shared__ __align__(16) unsigned short Bs[2][128 * 32];

    const int tid  = threadIdx.x;
    const int wave = tid >> 6;
    const int lane = tid & 63;
    const int bm = blockIdx.y * 128;
    const int bn = blockIdx.x * 128;
    const int wm = (wave >> 1) * 64;
    const int wn = (wave & 1) * 64;
    const int lr = lane & 15;   // row-in-16 for frags / col for C
    const int q  = lane >> 4;   // k-quad for frags / row-quad for C

    // staging coords: each wave stages rows [wave*32, wave*32+32) of both tiles,
    // 2 issues per operand (64 lanes * 16B = 16 rows * 64B per issue).
    const int srow = wave * 32;
    const int lrow = lane >> 2;        // 0..15
    const int lcol = (lane & 3) * 8;   // k-element offset

    f32x4 acc[4][4] = {};

    auto stage = [&](int buf, int k0) {
        #pragma unroll
        for (int h = 0; h < 2; ++h) {
            const int r = srow + h * 16;
            load16_lds(A + (size_t)(bm + r + lrow) * N + k0 + lcol, (void*)&As[buf][r * 32]);
            load16_lds(B + (size_t)(bn + r + lrow) * N + k0 + lcol, (void*)&Bs[buf][r * 32]);
        }
    };

    stage(0, 0);
    constexpr int KT = N / 32;
    for (int kt = 0; kt < KT; ++kt) {
        const int cur = kt & 1;
        __syncthreads();   // drains vmcnt: buf[cur] (staged one full iter ago) is ready
        bf16x8 af[4], bfr[4];
        #pragma unroll
        for (int mi = 0; mi < 4; ++mi)
            af[mi] = *(const bf16x8*)&As[cur][(wm + mi * 16 + lr) * 32 + q * 8];
        #pragma unroll
        for (int nj = 0; nj < 4; ++nj)
            bfr[nj] = *(const bf16x8*)&Bs[cur][(wn + nj * 16 + lr) * 32 + q * 8];
        if (kt + 1 < KT) stage(cur ^ 1, (kt + 1) * 32);  // prefetch next tile
        #pragma unroll
        for (int mi = 0; mi < 4; ++mi)
            #pragma unroll
            for (int nj = 0; nj < 4; ++nj)
                acc[mi][nj] = __builtin_amdgcn_mfma_f32_16x16x32_bf16(af[mi], bfr[nj], acc[mi][nj], 0, 0, 0);
    }

    const float sc = scale_p ? *scale_p : 1.0f;

    if constexpr (MODE == 0 || MODE == 1) {
        #pragma unroll
        for (int mi = 0; mi < 4; ++mi)
            #pragma unroll
            for (int nj = 0; nj < 4; ++nj)
                #pragma unroll
                for (int r = 0; r < 4; ++r) {
                    const int row = bm + wm + mi * 16 + q * 4 + r;  // C/D: row = quad*4+reg
                    const int col = bn + wn + nj * 16 + lr;         //      col = lane&15
                    float v = acc[mi][nj][r] * sc;
                    if constexpr (MODE == 1) v = (row == col ? 1.5f : 0.0f) - 0.5f * v;
                    Cb[(size_t)row * N + col] = f2bf(v);
                }
    } else if constexpr (MODE == 2) {
        float ltot = 0.f;
        #pragma unroll
        for (int mi = 0; mi < 4; ++mi) {
            #pragma unroll
            for (int r = 0; r < 4; ++r) {
                const int row = bm + wm + mi * 16 + q * 4 + r;
                float rs = 0.f;
                #pragma unroll
                for (int nj = 0; nj < 4; ++nj) {
                    float v = acc[mi][nj][r] * sc;
                    Cf[(size_t)row * N + (bn + wn + nj * 16 + lr)] = v;
                    rs += v;
                }
                ltot += rs;
                rs += __shfl_xor(rs, 1, 64);
                rs += __shfl_xor(rs, 2, 64);
                rs += __shfl_xor(rs, 4, 64);
                rs += __shfl_xor(rs, 8, 64);
                if (lr == 0) atomicAdd(&rowsum[row], rs);
            }
        }
        #pragma unroll
        for (int nj = 0; nj < 4; ++nj) {
            float cs = 0.f;
            #pragma unroll
            for (int mi = 0; mi < 4; ++mi)
                #pragma unroll
                for (int r = 0; r < 4; ++r) cs += acc[mi][nj][r];
            cs *= sc;
            cs += __shfl_xor(cs, 16, 64);
            cs += __shfl_xor(cs, 32, 64);
            if (q == 0) atomicAdd(&colsum[bn + wn + nj * 16 + lr], cs);
        }
        #pragma unroll
        for (int s = 1; s < 64; s <<= 1) ltot += __shfl_xor(ltot, s, 64);
        if (lane == 0) atomicAdd(tot, ltot);
    } else {  // MODE 3: Frobenius^2
        float s2 = 0.f;
        #pragma unroll
        for (int mi = 0; mi < 4; ++mi)
            #pragma unroll
            for (int nj = 0; nj < 4; ++nj)
                #pragma unroll
                for (int r = 0; r < 4; ++r) s2 += acc[mi][nj][r] * acc[mi][nj][r];
        #pragma unroll
        for (int s = 1; s < 64; s <<= 1) s2 += __shfl_xor(s2, s, 64);
        if (lane == 0) atomicAdd(tot, s2);
    }
}

// ---------------------------------------------------------------------------
// Small n^2 / n kernels
// ---------------------------------------------------------------------------
__global__ __launch_bounds__(256) void rowsum_kernel(const float* __restrict__ M, float* __restrict__ out) {
    const int row = blockIdx.x;
    float s = 0.f;
    for (int j = threadIdx.x; j < N; j += 256) s += M[(size_t)row * N + j];
    #pragma unroll
    for (int sh = 1; sh < 64; sh <<= 1) s += __shfl_xor(s, sh, 64);
    __shared__ float red[4];
    if ((threadIdx.x & 63) == 0) red[threadIdx.x >> 6] = s;
    __syncthreads();
    if (threadIdx.x == 0) out[row] = red[0] + red[1] + red[2] + red[3];
}

__global__ __launch_bounds__(256) void colsum_kernel(const float* __restrict__ M, float* __restrict__ out) {
    const int col = blockIdx.x * 256 + threadIdx.x;
    const int r0  = blockIdx.y * 64;
    float s = 0.f;
    for (int r = r0; r < r0 + 64; ++r) s += M[(size_t)r * N + col];
    atomicAdd(&out[col], s);
}

__global__ __launch_bounds__(256) void total_kernel(const float* __restrict__ rs, float* __restrict__ tot) {
    float s = 0.f;
    for (int i = threadIdx.x; i < N; i += 256) s += rs[i];
    #pragma unroll
    for (int sh = 1; sh < 64; sh <<= 1) s += __shfl_xor(s, sh, 64);
    __shared__ float red[4];
    if ((threadIdx.x & 63) == 0) red[threadIdx.x >> 6] = s;
    __syncthreads();
    if (threadIdx.x == 0) *tot = red[0] + red[1] + red[2] + red[3];
}

// X = P H P = H - rowmean_i - colmean_j + totalmean; write fp32 + bf16.
__global__ __launch_bounds__(256)
void project_kernel(const float* __restrict__ H, const float* __restrict__ rowsum,
                    const float* __restrict__ colsum, const float* __restrict__ tot,
                    float* __restrict__ Xf, unsigned short* __restrict__ Xb)
{
    constexpr float invn = 1.0f / N;
    const float tm = *tot * invn * invn;
    const size_t i4 = ((size_t)blockIdx.x * 256 + threadIdx.x) * 4;
    const int row = (int)(i4 >> 11);
    const int col = (int)(i4 & (N - 1));
    const float rm = rowsum[row] * invn;
    const float4 h = *(const float4*)(H + i4);
    float v0 = h.x - rm - colsum[col + 0] * invn + tm;
    float v1 = h.y - rm - colsum[col + 1] * invn + tm;
    float v2 = h.z - rm - colsum[col + 2] * invn + tm;
    float v3 = h.w - rm - colsum[col + 3] * invn + tm;
    *(float4*)(Xf + i4) = make_float4(v0, v1, v2, v3);
    ushort4 o; o.x = f2bf(v0); o.y = f2bf(v1); o.z = f2bf(v2); o.w = f2bf(v3);
    *(ushort4*)(Xb + i4) = o;
}

// s' = (sum of squares of (X X^T)^8)^(1/32) * 1.02 ; inv_s = 1/s'
__global__ void finalize_kernel(const float* __restrict__ sumsq, float* __restrict__ inv_s) {
    const float F2 = *sumsq;
    const float s = powf(F2, 1.0f / 32.0f) * 1.02f + 1e-8f;
    *inv_s = 1.0f / s;
}

// B0 = X * inv_s -> bf16 normal + bf16 transposed (tiled via LDS)
__global__ __launch_bounds__(256)
void scale_kernel(const float* __restrict__ Xf, const float* __restrict__ inv_s,
                  unsigned short* __restrict__ Bb, unsigned short* __restrict__ BTb)
{
    __shared__ unsigned short tile[64][65];
    const float is = *inv_s;
    const int bx = blockIdx.x * 64, by = blockIdx.y * 64;
    const int tx = threadIdx.x & 63, ty = threadIdx.x >> 6;
    for (int r = ty; r < 64; r += 4) {
        const float v = Xf[(size_t)(by + r) * N + bx + tx] * is;
        const unsigned short b = f2bf(v);
        Bb[(size_t)(by + r) * N + bx + tx] = b;
        tile[r][tx] = b;
    }
    __syncthreads();
    for (int r = ty; r < 64; r += 4)
        BTb[(size_t)(bx + r) * N + by + tx] = tile[tx][r];
}

// Re-center B_next = P * Bn * P using its row/col/total sums.
// FINAL=0: emit bf16 B + bf16 B^T for the next step.
// FINAL=1: emit H = centered + 1/n (fp32, in place in d_out).
template<int FINAL>
__global__ __launch_bounds__(256)
void center_kernel(float* __restrict__ Bn, const float* __restrict__ rowsum,
                   const float* __restrict__ colsum, const float* __restrict__ tot,
                   unsigned short* __restrict__ Bb, unsigned short* __restrict__ BTb)
{
    __shared__ unsigned short tile[64][65];
    constexpr float invn = 1.0f / N;
    const float tm = *tot * invn * invn;
    const int bx = blockIdx.x * 64, by = blockIdx.y * 64;
    const int tx = threadIdx.x & 63, ty = threadIdx.x >> 6;
    for (int r = ty; r < 64; r += 4) {
        const size_t idx = (size_t)(by + r) * N + bx + tx;
        const float v = Bn[idx] - rowsum[by + r] * invn - colsum[bx + tx] * invn + tm;
        if constexpr (FINAL) {
            Bn[idx] = v + invn;   // + e0 e0^T (entries 1/n)
        } else {
            const unsigned short b = f2bf(v);
            Bb[idx] = b;
            tile[r][tx] = b;
        }
    }
    if constexpr (!FINAL) {
        __syncthreads();
        for (int r = ty; r < 64; r += 4)
            BTb[(size_t)(bx + r) * N + by + tx] = tile[tx][r];
    }
}

// ---------------------------------------------------------------------------
extern "C" void kernel_launch(void* const* d_in, const int* in_sizes, int n_in,
                              void* d_out, int out_size, void* d_ws, size_t ws_size,
                              hipStream_t stream)
{
    const float* H_raw = (const float*)d_in[0];   // 2048x2048 fp32; d_in[1] (U) unused
    float* F32A = (float*)d_out;                  // fp32 staging + final H

    char* ws = (char*)d_ws;                       // needs ~25.2 MB
    unsigned short* Bb  = (unsigned short*)(ws);
    unsigned short* BTb = (unsigned short*)(ws + 8388608);
    unsigned short* Mb  = (unsigned short*)(ws + 16777216);
    float* rowsum = (float*)(ws + 25165824);
    float* colsum = rowsum + N;
    float* total  = colsum + N;     // rowsum..total contiguous for memset
    float* sumsq  = total + 1;
    float* inv_s  = total + 2;

    const dim3 gg(16, 16);          // 256 GEMM blocks (1/CU)
    const dim3 gt(32, 32);          // 64x64 tile kernels

    // zero accumulators (ws is poisoned 0xAA before every call)
    hipMemsetAsync(rowsum, 0, (size_t)(2 * N + 2) * sizeof(float), stream);

    // ---- projection: X = P H P ----
    rowsum_kernel<<<N, 256, 0, stream>>>(H_raw, rowsum);
    colsum_kernel<<<dim3(8, 32), 256, 0, stream>>>(H_raw, colsum);
    total_kernel<<<1, 256, 0, stream>>>(rowsum, total);
    project_kernel<<<4096, 256, 0, stream>>>(H_raw, rowsum, colsum, total, F32A, Bb);

    // ---- spectral-norm estimate by repeated squaring ----
    gemm_bt<0><<<gg, 256, 0, stream>>>(Bb, Bb, Mb, nullptr, nullptr, nullptr, nullptr, nullptr);   // G1=XX^T
    gemm_bt<0><<<gg, 256, 0, stream>>>(Mb, Mb, BTb, nullptr, nullptr, nullptr, nullptr, nullptr);  // G2=G1^2
    gemm_bt<0><<<gg, 256, 0, stream>>>(BTb, BTb, Bb, nullptr, nullptr, nullptr, nullptr, nullptr); // G3=G2^2
    gemm_bt<3><<<gg, 256, 0, stream>>>(Bb, Bb, nullptr, nullptr, nullptr, nullptr, sumsq, nullptr);// ||G3^2||_F^2
    finalize_kernel<<<1, 1, 0, stream>>>(sumsq, inv_s);
    scale_kernel<<<gt, 256, 0, stream>>>(F32A, inv_s, Bb, BTb);   // B0 = X/s (bf16 + bf16^T)

    // ---- Newton-Schulz: B <- (1.5I - 0.5 B B^T) B, re-centered each step ----
    for (int step = 0; step < NSTEPS; ++step) {
        gemm_bt<1><<<gg, 256, 0, stream>>>(Bb, Bb, Mb, nullptr, nullptr, nullptr, nullptr, nullptr);
        hipMemsetAsync(rowsum, 0, (size_t)(2 * N + 1) * sizeof(float), stream);
        gemm_bt<2><<<gg, 256, 0, stream>>>(Mb, BTb, nullptr, F32A, rowsum, colsum, total, nullptr);
        if (step < NSTEPS - 1)
            center_kernel<0><<<gt, 256, 0, stream>>>(F32A, rowsum, colsum, total, Bb, BTb);
        else
            center_kernel<1><<<gt, 256, 0, stream>>>(F32A, rowsum, colsum, total, nullptr, nullptr);
    }
}

// Round 2
// 633.161 us; speedup vs baseline: 1.5892x; 1.5892x over previous
//
#include <hip/hip_runtime.h>
#include <hip/hip_bf16.h>
#include <cstdint>

// ============================================================================
// IsoNSProject: H = e0 e0^T + polar(P H_raw P) restricted to 1-perp subspace.
// NS iteration conjugated into n-dim space (U never materialized):
//   B0 = P H P / s,  B <- (1.5 I - 0.5 B B^T) B,  H = B_final + 1/n.
// Spectral norm s via 4 Gram power iterations (Rayleigh quotient, x1.06
// safety; NS converges for sigma0 in (0, sqrt(3)) so +-30% accuracy is fine).
// GEMM: 128x128 tile, BK=64, double-buffered global_load_lds with XOR-swizzled
// LDS layout (conflict-free frag reads) and DMA issued at iteration top so the
// vmcnt(0) barrier drain is covered by a full compute phase.
// ============================================================================

#define N 2048
#define NSTEPS 6

typedef __bf16 bf16x8 __attribute__((ext_vector_type(8)));
typedef float  f32x4  __attribute__((ext_vector_type(4)));

typedef const void __attribute__((address_space(1))) gvoid;
typedef void __attribute__((address_space(3)))       svoid;

__device__ __forceinline__ void load16_lds(const void* g, void* l) {
    // 16B direct global->LDS DMA; LDS dest = wave-uniform base + lane*16.
    __builtin_amdgcn_global_load_lds((gvoid*)(uintptr_t)g,
                                     (svoid*)(uint32_t)(uintptr_t)l, 16, 0, 0);
}

__device__ __forceinline__ unsigned short f2bf(float x) {
    __hip_bfloat16 h = __float2bfloat16(x);   // RNE
    return *reinterpret_cast<unsigned short*>(&h);
}
__device__ __forceinline__ float u2f(unsigned u) { float f; __builtin_memcpy(&f, &u, 4); return f; }
__device__ __forceinline__ float bflo(unsigned u) { return u2f(u << 16); }
__device__ __forceinline__ float bfhi(unsigned u) { return u2f(u & 0xFFFF0000u); }
__device__ __forceinline__ float b2f(unsigned short b) { return u2f(((unsigned)b) << 16); }

// ---------------------------------------------------------------------------
// GEMM: C = A * B^T (both operands row-major [row][k]), 2048^3, bf16 MFMA.
// 128x128 block tile, BK=64, 256 threads (4 waves, 2x2 of 64x64 wave tiles).
// LDS layout swizzled: 16B slot(r, c) = r*8 + (c ^ (r&7)); since the DMA lane
// layout is fixed (base + lane*16) the swizzle is applied to the global SOURCE
// address per lane. Frag reads then hit 2 lanes/bank (free).
// MODE 1: Cb = bf16(1.5*I - 0.5*acc)          (the NS "M" matrix)
// MODE 2: Cf = acc (fp32) + row/col/total sum atomics (for re-centering)
// ---------------------------------------------------------------------------
template<int MODE>
__global__ __launch_bounds__(256, 1)
void gemm_bt(const unsigned short* __restrict__ A, const unsigned short* __restrict__ B,
             unsigned short* __restrict__ Cb, float* __restrict__ Cf,
             float* __restrict__ rowsum, float* __restrict__ colsum,
             float* __restrict__ tot)
{
    __shared__ __align__(16) unsigned short As[2][128 * 64];  // 16 KB per buffer
    __shared__ __align__(16) unsigned short Bs[2][128 * 64];

    const int tid  = threadIdx.x;
    const int wave = tid >> 6;
    const int lane = tid & 63;
    const int bm = blockIdx.y * 128;
    const int bn = blockIdx.x * 128;
    const int wm = (wave >> 1) * 64;
    const int wn = (wave & 1) * 64;
    const int lr = lane & 15;   // row-in-16 for frags / col for C
    const int q  = lane >> 4;   // k-quad for frags / row-quad for C
    const int l7 = lr & 7;

    f32x4 acc[4][4] = {};

    // Stage one BK=64 K-slab of both tiles into buf. Each wave issues 4 DMAs
    // per operand (64 lanes x 16B = 8 rows x 128B each). Lane's global source
    // is chunk c = (lane&7) ^ ((lane>>3)&7) of row rr -> XOR-swizzled layout.
    auto stage = [&](int buf, int k0) {
        #pragma unroll
        for (int j = 0; j < 4; ++j) {
            const int s0 = (wave * 4 + j) * 64;                   // slot base (wave-uniform)
            const int rr = (s0 >> 3) + (lane >> 3);               // row 0..127
            const int cc = (lane & 7) ^ ((lane >> 3) & 7);        // k-chunk 0..7
            const size_t go = (size_t)k0 + cc * 8;
            load16_lds(A + (size_t)(bm + rr) * N + go, (void*)&As[buf][s0 * 8]);
            load16_lds(B + (size_t)(bn + rr) * N + go, (void*)&Bs[buf][s0 * 8]);
        }
    };

    stage(0, 0);
    constexpr int KT = N / 64;
    for (int kt = 0; kt < KT; ++kt) {
        const int cur = kt & 1;
        __syncthreads();   // vmcnt(0) drain: buf[cur]'s DMA (issued a full iter ago) lands
        // issue next slab IMMEDIATELY so the whole iteration covers its latency;
        // buf[cur^1] was last read before the barrier we just crossed -> safe.
        if (kt + 1 < KT) stage(cur ^ 1, (kt + 1) * 64);

        bf16x8 af[2][4], bfr[2][4];
        #pragma unroll
        for (int kk = 0; kk < 2; ++kk)
            #pragma unroll
            for (int mi = 0; mi < 4; ++mi) {
                const int rA = wm + mi * 16 + lr;
                const int rB = wn + mi * 16 + lr;
                const int cs = (kk * 4 + q) ^ l7;
                af [kk][mi] = *(const bf16x8*)&As[cur][(rA * 8 + cs) * 8];
                bfr[kk][mi] = *(const bf16x8*)&Bs[cur][(rB * 8 + cs) * 8];
            }
        #pragma unroll
        for (int kk = 0; kk < 2; ++kk)
            #pragma unroll
            for (int mi = 0; mi < 4; ++mi)
                #pragma unroll
                for (int nj = 0; nj < 4; ++nj)
                    acc[mi][nj] = __builtin_amdgcn_mfma_f32_16x16x32_bf16(af[kk][mi], bfr[kk][nj], acc[mi][nj], 0, 0, 0);
    }

    if constexpr (MODE == 1) {
        #pragma unroll
        for (int mi = 0; mi < 4; ++mi)
            #pragma unroll
            for (int nj = 0; nj < 4; ++nj)
                #pragma unroll
                for (int r = 0; r < 4; ++r) {
                    const int row = bm + wm + mi * 16 + q * 4 + r;  // C/D: row = quad*4+reg
                    const int col = bn + wn + nj * 16 + lr;         //      col = lane&15
                    const float v = (row == col ? 1.5f : 0.0f) - 0.5f * acc[mi][nj][r];
                    Cb[(size_t)row * N + col] = f2bf(v);
                }
    } else {  // MODE 2
        float ltot = 0.f;
        #pragma unroll
        for (int mi = 0; mi < 4; ++mi) {
            #pragma unroll
            for (int r = 0; r < 4; ++r) {
                const int row = bm + wm + mi * 16 + q * 4 + r;
                float rs = 0.f;
                #pragma unroll
                for (int nj = 0; nj < 4; ++nj) {
                    const float v = acc[mi][nj][r];
                    Cf[(size_t)row * N + (bn + wn + nj * 16 + lr)] = v;
                    rs += v;
                }
                ltot += rs;
                rs += __shfl_xor(rs, 1, 64);
                rs += __shfl_xor(rs, 2, 64);
                rs += __shfl_xor(rs, 4, 64);
                rs += __shfl_xor(rs, 8, 64);
                if (lr == 0) atomicAdd(&rowsum[row], rs);
            }
        }
        #pragma unroll
        for (int nj = 0; nj < 4; ++nj) {
            float cs = 0.f;
            #pragma unroll
            for (int mi = 0; mi < 4; ++mi)
                #pragma unroll
                for (int r = 0; r < 4; ++r) cs += acc[mi][nj][r];
            cs += __shfl_xor(cs, 16, 64);
            cs += __shfl_xor(cs, 32, 64);
            if (q == 0) atomicAdd(&colsum[bn + wn + nj * 16 + lr], cs);
        }
        #pragma unroll
        for (int s = 1; s < 64; s <<= 1) ltot += __shfl_xor(ltot, s, 64);
        if (lane == 0) atomicAdd(tot, ltot);
    }
}

// ---------------------------------------------------------------------------
// Small n^2 / n kernels
// ---------------------------------------------------------------------------
__global__ __launch_bounds__(256) void rowsum_kernel(const float* __restrict__ M, float* __restrict__ out) {
    const int row = blockIdx.x;
    float s = 0.f;
    for (int j = threadIdx.x; j < N; j += 256) s += M[(size_t)row * N + j];
    #pragma unroll
    for (int sh = 1; sh < 64; sh <<= 1) s += __shfl_xor(s, sh, 64);
    __shared__ float red[4];
    if ((threadIdx.x & 63) == 0) red[threadIdx.x >> 6] = s;
    __syncthreads();
    if (threadIdx.x == 0) out[row] = red[0] + red[1] + red[2] + red[3];
}

__global__ __launch_bounds__(256) void colsum_kernel(const float* __restrict__ M, float* __restrict__ out) {
    const int col = blockIdx.x * 256 + threadIdx.x;
    const int r0  = blockIdx.y * 64;
    float s = 0.f;
    for (int r = r0; r < r0 + 64; ++r) s += M[(size_t)r * N + col];
    atomicAdd(&out[col], s);
}

__global__ __launch_bounds__(256) void total_kernel(const float* __restrict__ rs, float* __restrict__ tot) {
    float s = 0.f;
    for (int i = threadIdx.x; i < N; i += 256) s += rs[i];
    #pragma unroll
    for (int sh = 1; sh < 64; sh <<= 1) s += __shfl_xor(s, sh, 64);
    __shared__ float red[4];
    if ((threadIdx.x & 63) == 0) red[threadIdx.x >> 6] = s;
    __syncthreads();
    if (threadIdx.x == 0) *tot = red[0] + red[1] + red[2] + red[3];
}

// X = P H P = H - rowmean_i - colmean_j + totalmean; write fp32 + bf16.
__global__ __launch_bounds__(256)
void project_kernel(const float* __restrict__ H, const float* __restrict__ rowsum,
                    const float* __restrict__ colsum, const float* __restrict__ tot,
                    float* __restrict__ Xf, unsigned short* __restrict__ Xb)
{
    constexpr float invn = 1.0f / N;
    const float tm = *tot * invn * invn;
    const size_t i4 = ((size_t)blockIdx.x * 256 + threadIdx.x) * 4;
    const int row = (int)(i4 >> 11);
    const int col = (int)(i4 & (N - 1));
    const float rm = rowsum[row] * invn;
    const float4 h = *(const float4*)(H + i4);
    float v0 = h.x - rm - colsum[col + 0] * invn + tm;
    float v1 = h.y - rm - colsum[col + 1] * invn + tm;
    float v2 = h.z - rm - colsum[col + 2] * invn + tm;
    float v3 = h.w - rm - colsum[col + 3] * invn + tm;
    *(float4*)(Xf + i4) = make_float4(v0, v1, v2, v3);
    ushort4 o; o.x = f2bf(v0); o.y = f2bf(v1); o.z = f2bf(v2); o.w = f2bf(v3);
    *(ushort4*)(Xb + i4) = o;
}

// ---- power iteration on the Gram matrix X^T X (X in bf16) ----
__global__ void init_v(float* __restrict__ v) {
    const int i = blockIdx.x * 256 + threadIdx.x;
    unsigned u = (unsigned)i * 2654435761u; u ^= u >> 16; u *= 2246822519u; u ^= u >> 13;
    v[i] = (float)(u & 0xFFFF) * (1.0f / 65536.0f) - 0.5f;
}

// y = X v  (row-wise dot; 8 rows/block, 32 lanes/row)
__global__ __launch_bounds__(256)
void matvec_row(const unsigned short* __restrict__ X, const float* __restrict__ v,
                float* __restrict__ y)
{
    const int r = blockIdx.x * 8 + (threadIdx.x >> 5);
    const int l = threadIdx.x & 31;
    const unsigned short* row = X + (size_t)r * N;
    float s = 0.f;
    #pragma unroll
    for (int kk = 0; kk < 8; ++kk) {
        const int c0 = kk * 256 + l * 8;
        const uint4  u  = *(const uint4*)(row + c0);
        const float4 va = *(const float4*)(v + c0);
        const float4 vb = *(const float4*)(v + c0 + 4);
        s += bflo(u.x) * va.x + bfhi(u.x) * va.y + bflo(u.y) * va.z + bfhi(u.y) * va.w
           + bflo(u.z) * vb.x + bfhi(u.z) * vb.y + bflo(u.w) * vb.z + bfhi(u.w) * vb.w;
    }
    #pragma unroll
    for (int sh = 1; sh < 32; sh <<= 1) s += __shfl_xor(s, sh, 64);
    if (l == 0) y[r] = s;
}

// vout += X^T y (vout pre-zeroed; 64-row strips, coalesced cols)
__global__ __launch_bounds__(256)
void matvec_colT(const unsigned short* __restrict__ X, const float* __restrict__ y,
                 float* __restrict__ vout)
{
    const int j  = blockIdx.x * 256 + threadIdx.x;
    const int r0 = blockIdx.y * 64;
    float s = 0.f;
    #pragma unroll 4
    for (int r = r0; r < r0 + 64; ++r) s += b2f(X[(size_t)r * N + j]) * y[r];
    atomicAdd(&vout[j], s);
}

__global__ __launch_bounds__(256) void sumsq_kernel(const float* __restrict__ x, float* __restrict__ out) {
    float s = 0.f;
    for (int i = threadIdx.x; i < N; i += 256) { const float v = x[i]; s += v * v; }
    #pragma unroll
    for (int sh = 1; sh < 64; sh <<= 1) s += __shfl_xor(s, sh, 64);
    __shared__ float red[4];
    if ((threadIdx.x & 63) == 0) red[threadIdx.x >> 6] = s;
    __syncthreads();
    if (threadIdx.x == 0) *out = red[0] + red[1] + red[2] + red[3];
}

// s_est = sqrt(||Xv||^2 / ||v||^2) <= sigma_max (Rayleigh); inv_s = 1/(1.06 s)
__global__ void rayleigh_kernel(const float* __restrict__ sy, const float* __restrict__ sv,
                                float* __restrict__ inv_s) {
    *inv_s = sqrtf(*sv / (*sy + 1e-30f)) * (1.0f / 1.06f);
}

// B0 = X * inv_s -> bf16 normal + bf16 transposed (tiled via LDS)
__global__ __launch_bounds__(256)
void scale_kernel(const float* __restrict__ Xf, const float* __restrict__ inv_s,
                  unsigned short* __restrict__ Bb, unsigned short* __restrict__ BTb)
{
    __shared__ unsigned short tile[64][65];
    const float is = *inv_s;
    const int bx = blockIdx.x * 64, by = blockIdx.y * 64;
    const int tx = threadIdx.x & 63, ty = threadIdx.x >> 6;
    for (int r = ty; r < 64; r += 4) {
        const float v = Xf[(size_t)(by + r) * N + bx + tx] * is;
        const unsigned short b = f2bf(v);
        Bb[(size_t)(by + r) * N + bx + tx] = b;
        tile[r][tx] = b;
    }
    __syncthreads();
    for (int r = ty; r < 64; r += 4)
        BTb[(size_t)(bx + r) * N + by + tx] = tile[tx][r];
}

// Re-center B_next = P * Bn * P using its row/col/total sums.
// FINAL=0: emit bf16 B + bf16 B^T for the next step.
// FINAL=1: emit H = centered + 1/n (fp32, in place in d_out).
template<int FINAL>
__global__ __launch_bounds__(256)
void center_kernel(float* __restrict__ Bn, const float* __restrict__ rowsum,
                   const float* __restrict__ colsum, const float* __restrict__ tot,
                   unsigned short* __restrict__ Bb, unsigned short* __restrict__ BTb)
{
    __shared__ unsigned short tile[64][65];
    constexpr float invn = 1.0f / N;
    const float tm = *tot * invn * invn;
    const int bx = blockIdx.x * 64, by = blockIdx.y * 64;
    const int tx = threadIdx.x & 63, ty = threadIdx.x >> 6;
    for (int r = ty; r < 64; r += 4) {
        const size_t idx = (size_t)(by + r) * N + bx + tx;
        const float v = Bn[idx] - rowsum[by + r] * invn - colsum[bx + tx] * invn + tm;
        if constexpr (FINAL) {
            Bn[idx] = v + invn;   // + e0 e0^T (entries 1/n)
        } else {
            const unsigned short b = f2bf(v);
            Bb[idx] = b;
            tile[r][tx] = b;
        }
    }
    if constexpr (!FINAL) {
        __syncthreads();
        for (int r = ty; r < 64; r += 4)
            BTb[(size_t)(bx + r) * N + by + tx] = tile[tx][r];
    }
}

// ---------------------------------------------------------------------------
extern "C" void kernel_launch(void* const* d_in, const int* in_sizes, int n_in,
                              void* d_out, int out_size, void* d_ws, size_t ws_size,
                              hipStream_t stream)
{
    const float* H_raw = (const float*)d_in[0];   // 2048x2048 fp32; d_in[1] (U) unused
    float* F32A = (float*)d_out;                  // fp32 staging + final H

    char* ws = (char*)d_ws;                       // ~25.3 MB used
    unsigned short* Bb  = (unsigned short*)(ws);
    unsigned short* BTb = (unsigned short*)(ws + 8388608);
    unsigned short* Mb  = (unsigned short*)(ws + 16777216);
    float* base   = (float*)(ws + 25165824);
    float* rowsum = base;             // N
    float* colsum = base + 2048;      // N
    float* total  = base + 4096;
    float* sumsq_y = base + 4097;
    float* sumsq_v = base + 4098;
    float* inv_s   = base + 4099;
    float* va = base + 4100;          // N (16B-aligned: 4100*4 % 16 == 0)
    float* vb = base + 6148;          // N
    float* yv = base + 8196;          // N

    const dim3 gg(16, 16);            // 256 GEMM blocks (1/CU)
    const dim3 gt(32, 32);            // 64x64 tile kernels

    hipMemsetAsync(rowsum, 0, (size_t)(2 * N + 3) * sizeof(float), stream);

    // ---- projection: X = P H P ----
    rowsum_kernel<<<N, 256, 0, stream>>>(H_raw, rowsum);
    colsum_kernel<<<dim3(8, 32), 256, 0, stream>>>(H_raw, colsum);
    total_kernel<<<1, 256, 0, stream>>>(rowsum, total);
    project_kernel<<<4096, 256, 0, stream>>>(H_raw, rowsum, colsum, total, F32A, Bb);

    // ---- spectral-norm estimate: 4 Gram power iterations + Rayleigh ----
    init_v<<<8, 256, 0, stream>>>(va);
    float *pa = va, *pb = vb;
    for (int it = 0; it < 4; ++it) {
        matvec_row<<<256, 256, 0, stream>>>(Bb, pa, yv);
        hipMemsetAsync(pb, 0, N * sizeof(float), stream);
        matvec_colT<<<dim3(8, 32), 256, 0, stream>>>(Bb, yv, pb);
        float* t = pa; pa = pb; pb = t;
    }
    sumsq_kernel<<<1, 256, 0, stream>>>(pa, sumsq_v);
    matvec_row<<<256, 256, 0, stream>>>(Bb, pa, yv);
    sumsq_kernel<<<1, 256, 0, stream>>>(yv, sumsq_y);
    rayleigh_kernel<<<1, 1, 0, stream>>>(sumsq_y, sumsq_v, inv_s);
    scale_kernel<<<gt, 256, 0, stream>>>(F32A, inv_s, Bb, BTb);   // B0 = X/s (bf16 + bf16^T)

    // ---- Newton-Schulz: B <- (1.5I - 0.5 B B^T) B, re-centered each step ----
    for (int step = 0; step < NSTEPS; ++step) {
        gemm_bt<1><<<gg, 256, 0, stream>>>(Bb, Bb, Mb, nullptr, nullptr, nullptr, nullptr);
        hipMemsetAsync(rowsum, 0, (size_t)(2 * N + 1) * sizeof(float), stream);
        gemm_bt<2><<<gg, 256, 0, stream>>>(Mb, BTb, nullptr, F32A, rowsum, colsum, total);
        if (step < NSTEPS - 1)
            center_kernel<0><<<gt, 256, 0, stream>>>(F32A, rowsum, colsum, total, Bb, BTb);
        else
            center_kernel<1><<<gt, 256, 0, stream>>>(F32A, rowsum, colsum, total, nullptr, nullptr);
    }
}

// Round 3
// 578.858 us; speedup vs baseline: 1.7383x; 1.0938x over previous
//
#include <hip/hip_runtime.h>
#include <hip/hip_bf16.h>
#include <cstdint>

// ============================================================================
// IsoNSProject: H = e0 e0^T + polar(P H_raw P) restricted to 1-perp subspace.
// NS iteration conjugated into n-dim space (U never materialized):
//   B0 = P H P / s,  B <- (1.5 I - 0.5 B B^T) B,  H = B_final + 1/n.
// Spectral norm s via 4 Gram power iterations + Rayleigh quotient (x1.06).
// GEMM: 128x64 tile -> 512 blocks = 2 blocks/CU (sibling-block overlap fills
// the vmcnt(0) barrier drain), BK=64, double-buffered global_load_lds with
// XOR-swizzled LDS layout, DMA issued at iteration top, XCD-compact mapping.
// NSTEPS=5: worst-case sigma(X0)>=0.62 -> orthogonality error ~5e-10 << noise.
// ============================================================================

#define N 2048
#define NSTEPS 5

typedef __bf16 bf16x8 __attribute__((ext_vector_type(8)));
typedef float  f32x4  __attribute__((ext_vector_type(4)));

typedef const void __attribute__((address_space(1))) gvoid;
typedef void __attribute__((address_space(3)))       svoid;

__device__ __forceinline__ void load16_lds(const void* g, void* l) {
    // 16B direct global->LDS DMA; LDS dest = wave-uniform base + lane*16.
    __builtin_amdgcn_global_load_lds((gvoid*)(uintptr_t)g,
                                     (svoid*)(uint32_t)(uintptr_t)l, 16, 0, 0);
}

__device__ __forceinline__ unsigned short f2bf(float x) {
    __hip_bfloat16 h = __float2bfloat16(x);   // RNE
    return *reinterpret_cast<unsigned short*>(&h);
}
__device__ __forceinline__ float u2f(unsigned u) { float f; __builtin_memcpy(&f, &u, 4); return f; }
__device__ __forceinline__ float bflo(unsigned u) { return u2f(u << 16); }
__device__ __forceinline__ float bfhi(unsigned u) { return u2f(u & 0xFFFF0000u); }
__device__ __forceinline__ float b2f(unsigned short b) { return u2f(((unsigned)b) << 16); }

// ---------------------------------------------------------------------------
// GEMM: C = A * B^T (both operands row-major [row][k]), 2048^3, bf16 MFMA.
// 128x64 block tile, BK=64, 256 threads (4 waves, 2x2 of 64x32 wave tiles).
// 512 blocks -> 2 blocks/CU resident (LDS 48 KB/block): sibling block's MFMA
// covers this block's barrier drain.
// LDS 16B-slot layout swizzled: slot(r,c) = r*8 + (c ^ (r&7)); the DMA lane
// layout is fixed (base + lane*16) so the swizzle is applied to the global
// SOURCE address per lane. Frag reads then hit 2 lanes/bank (free).
// Work mapping: XCD g = blk&7 owns a 4-row x 16-col tile region (A 2MB + B 4MB
// ~ L2-resident per XCD).
// MODE 1: Cb = bf16(1.5*I - 0.5*acc)          (the NS "M" matrix)
// MODE 2: Cf = acc (fp32) + row/col/total sum atomics (for re-centering)
// ---------------------------------------------------------------------------
template<int MODE>
__global__ __launch_bounds__(256, 2)
void gemm_bt(const unsigned short* __restrict__ A, const unsigned short* __restrict__ B,
             unsigned short* __restrict__ Cb, float* __restrict__ Cf,
             float* __restrict__ rowsum, float* __restrict__ colsum,
             float* __restrict__ tot)
{
    __shared__ __align__(16) unsigned short As[2][128 * 64];  // 16 KB / buffer
    __shared__ __align__(16) unsigned short Bs[2][64 * 64];   //  8 KB / buffer

    const int tid  = threadIdx.x;
    const int wave = tid >> 6;
    const int lane = tid & 63;

    // XCD-compact work mapping: 512 blocks, XCD g=id&7 gets rows[(g>>1)*4..+4),
    // cols[(g&1)*16..+16) of the 16x32 tile grid.
    const int id = blockIdx.x;
    const int g  = id & 7, w = id >> 3;
    const int bm = ((g >> 1) * 4 + (w >> 4)) * 128;
    const int bn = ((g & 1) * 16 + (w & 15)) * 64;

    const int wm = (wave >> 1) * 64;   // wave tile: 64 x 32
    const int wn = (wave & 1) * 32;
    const int lr = lane & 15;   // row-in-16 for frags / col for C
    const int q  = lane >> 4;   // k-quad for frags / row-quad for C
    const int l7 = lr & 7;

    f32x4 acc[4][2] = {};

    // Stage one BK=64 K-slab. A: 16 KB = 16 lane-chunk DMAs (4/wave);
    // B: 8 KB (2/wave). Lane's source chunk c = (lane&7)^((lane>>3)&7).
    auto stage = [&](int buf, int k0) {
        #pragma unroll
        for (int j = 0; j < 4; ++j) {
            const int s0 = (wave * 4 + j) * 64;
            const int rr = (s0 >> 3) + (lane >> 3);
            const int cc = (lane & 7) ^ ((lane >> 3) & 7);
            load16_lds(A + (size_t)(bm + rr) * N + k0 + cc * 8, (void*)&As[buf][s0 * 8]);
        }
        #pragma unroll
        for (int j = 0; j < 2; ++j) {
            const int s0 = (wave * 2 + j) * 64;
            const int rr = (s0 >> 3) + (lane >> 3);
            const int cc = (lane & 7) ^ ((lane >> 3) & 7);
            load16_lds(B + (size_t)(bn + rr) * N + k0 + cc * 8, (void*)&Bs[buf][s0 * 8]);
        }
    };

    stage(0, 0);
    constexpr int KT = N / 64;
    for (int kt = 0; kt < KT; ++kt) {
        const int cur = kt & 1;
        __syncthreads();   // vmcnt(0) drain: buf[cur]'s DMA (issued last iter) lands
        if (kt + 1 < KT) stage(cur ^ 1, (kt + 1) * 64);  // cover latency w/ full iter

        bf16x8 af[2][4], bfr[2][2];
        #pragma unroll
        for (int kk = 0; kk < 2; ++kk) {
            const int cs = (kk * 4 + q) ^ l7;
            #pragma unroll
            for (int mi = 0; mi < 4; ++mi)
                af[kk][mi] = *(const bf16x8*)&As[cur][((wm + mi * 16 + lr) * 8 + cs) * 8];
            #pragma unroll
            for (int nj = 0; nj < 2; ++nj)
                bfr[kk][nj] = *(const bf16x8*)&Bs[cur][((wn + nj * 16 + lr) * 8 + cs) * 8];
        }
        #pragma unroll
        for (int kk = 0; kk < 2; ++kk)
            #pragma unroll
            for (int mi = 0; mi < 4; ++mi)
                #pragma unroll
                for (int nj = 0; nj < 2; ++nj)
                    acc[mi][nj] = __builtin_amdgcn_mfma_f32_16x16x32_bf16(af[kk][mi], bfr[kk][nj], acc[mi][nj], 0, 0, 0);
    }

    if constexpr (MODE == 1) {
        #pragma unroll
        for (int mi = 0; mi < 4; ++mi)
            #pragma unroll
            for (int nj = 0; nj < 2; ++nj)
                #pragma unroll
                for (int r = 0; r < 4; ++r) {
                    const int row = bm + wm + mi * 16 + q * 4 + r;  // C/D: row = quad*4+reg
                    const int col = bn + wn + nj * 16 + lr;         //      col = lane&15
                    const float v = (row == col ? 1.5f : 0.0f) - 0.5f * acc[mi][nj][r];
                    Cb[(size_t)row * N + col] = f2bf(v);
                }
    } else {  // MODE 2
        float ltot = 0.f;
        #pragma unroll
        for (int mi = 0; mi < 4; ++mi) {
            #pragma unroll
            for (int r = 0; r < 4; ++r) {
                const int row = bm + wm + mi * 16 + q * 4 + r;
                float rs = 0.f;
                #pragma unroll
                for (int nj = 0; nj < 2; ++nj) {
                    const float v = acc[mi][nj][r];
                    Cf[(size_t)row * N + (bn + wn + nj * 16 + lr)] = v;
                    rs += v;
                }
                ltot += rs;
                rs += __shfl_xor(rs, 1, 64);
                rs += __shfl_xor(rs, 2, 64);
                rs += __shfl_xor(rs, 4, 64);
                rs += __shfl_xor(rs, 8, 64);
                if (lr == 0) atomicAdd(&rowsum[row], rs);
            }
        }
        #pragma unroll
        for (int nj = 0; nj < 2; ++nj) {
            float cs = 0.f;
            #pragma unroll
            for (int mi = 0; mi < 4; ++mi)
                #pragma unroll
                for (int r = 0; r < 4; ++r) cs += acc[mi][nj][r];
            cs += __shfl_xor(cs, 16, 64);
            cs += __shfl_xor(cs, 32, 64);
            if (q == 0) atomicAdd(&colsum[bn + wn + nj * 16 + lr], cs);
        }
        #pragma unroll
        for (int s = 1; s < 64; s <<= 1) ltot += __shfl_xor(ltot, s, 64);
        if (lane == 0) atomicAdd(tot, ltot);
    }
}

// ---------------------------------------------------------------------------
// Small n^2 / n kernels
// ---------------------------------------------------------------------------
__global__ __launch_bounds__(256) void rowsum_kernel(const float* __restrict__ M, float* __restrict__ out) {
    const int row = blockIdx.x;
    float s = 0.f;
    for (int j = threadIdx.x; j < N; j += 256) s += M[(size_t)row * N + j];
    #pragma unroll
    for (int sh = 1; sh < 64; sh <<= 1) s += __shfl_xor(s, sh, 64);
    __shared__ float red[4];
    if ((threadIdx.x & 63) == 0) red[threadIdx.x >> 6] = s;
    __syncthreads();
    if (threadIdx.x == 0) out[row] = red[0] + red[1] + red[2] + red[3];
}

__global__ __launch_bounds__(256) void colsum_kernel(const float* __restrict__ M, float* __restrict__ out) {
    const int col = blockIdx.x * 256 + threadIdx.x;
    const int r0  = blockIdx.y * 64;
    float s = 0.f;
    for (int r = r0; r < r0 + 64; ++r) s += M[(size_t)r * N + col];
    atomicAdd(&out[col], s);
}

__global__ __launch_bounds__(256) void total_kernel(const float* __restrict__ rs, float* __restrict__ tot) {
    float s = 0.f;
    for (int i = threadIdx.x; i < N; i += 256) s += rs[i];
    #pragma unroll
    for (int sh = 1; sh < 64; sh <<= 1) s += __shfl_xor(s, sh, 64);
    __shared__ float red[4];
    if ((threadIdx.x & 63) == 0) red[threadIdx.x >> 6] = s;
    __syncthreads();
    if (threadIdx.x == 0) *tot = red[0] + red[1] + red[2] + red[3];
}

// X = P H P = H - rowmean_i - colmean_j + totalmean; write fp32 + bf16.
__global__ __launch_bounds__(256)
void project_kernel(const float* __restrict__ H, const float* __restrict__ rowsum,
                    const float* __restrict__ colsum, const float* __restrict__ tot,
                    float* __restrict__ Xf, unsigned short* __restrict__ Xb)
{
    constexpr float invn = 1.0f / N;
    const float tm = *tot * invn * invn;
    const size_t i4 = ((size_t)blockIdx.x * 256 + threadIdx.x) * 4;
    const int row = (int)(i4 >> 11);
    const int col = (int)(i4 & (N - 1));
    const float rm = rowsum[row] * invn;
    const float4 h = *(const float4*)(H + i4);
    float v0 = h.x - rm - colsum[col + 0] * invn + tm;
    float v1 = h.y - rm - colsum[col + 1] * invn + tm;
    float v2 = h.z - rm - colsum[col + 2] * invn + tm;
    float v3 = h.w - rm - colsum[col + 3] * invn + tm;
    *(float4*)(Xf + i4) = make_float4(v0, v1, v2, v3);
    ushort4 o; o.x = f2bf(v0); o.y = f2bf(v1); o.z = f2bf(v2); o.w = f2bf(v3);
    *(ushort4*)(Xb + i4) = o;
}

// ---- power iteration on the Gram matrix X^T X (X in bf16) ----
__global__ void init_v(float* __restrict__ v) {
    const int i = blockIdx.x * 256 + threadIdx.x;
    unsigned u = (unsigned)i * 2654435761u; u ^= u >> 16; u *= 2246822519u; u ^= u >> 13;
    v[i] = (float)(u & 0xFFFF) * (1.0f / 65536.0f) - 0.5f;
}

// y = X v  (row-wise dot; 8 rows/block, 32 lanes/row)
__global__ __launch_bounds__(256)
void matvec_row(const unsigned short* __restrict__ X, const float* __restrict__ v,
                float* __restrict__ y)
{
    const int r = blockIdx.x * 8 + (threadIdx.x >> 5);
    const int l = threadIdx.x & 31;
    const unsigned short* row = X + (size_t)r * N;
    float s = 0.f;
    #pragma unroll
    for (int kk = 0; kk < 8; ++kk) {
        const int c0 = kk * 256 + l * 8;
        const uint4  u  = *(const uint4*)(row + c0);
        const float4 va = *(const float4*)(v + c0);
        const float4 vb = *(const float4*)(v + c0 + 4);
        s += bflo(u.x) * va.x + bfhi(u.x) * va.y + bflo(u.y) * va.z + bfhi(u.y) * va.w
           + bflo(u.z) * vb.x + bfhi(u.z) * vb.y + bflo(u.w) * vb.z + bfhi(u.w) * vb.w;
    }
    #pragma unroll
    for (int sh = 1; sh < 32; sh <<= 1) s += __shfl_xor(s, sh, 64);
    if (l == 0) y[r] = s;
}

// vout += X^T y (vout pre-zeroed; 64-row strips, coalesced cols)
__global__ __launch_bounds__(256)
void matvec_colT(const unsigned short* __restrict__ X, const float* __restrict__ y,
                 float* __restrict__ vout)
{
    const int j  = blockIdx.x * 256 + threadIdx.x;
    const int r0 = blockIdx.y * 64;
    float s = 0.f;
    #pragma unroll 4
    for (int r = r0; r < r0 + 64; ++r) s += b2f(X[(size_t)r * N + j]) * y[r];
    atomicAdd(&vout[j], s);
}

__global__ __launch_bounds__(256) void sumsq_kernel(const float* __restrict__ x, float* __restrict__ out) {
    float s = 0.f;
    for (int i = threadIdx.x; i < N; i += 256) { const float v = x[i]; s += v * v; }
    #pragma unroll
    for (int sh = 1; sh < 64; sh <<= 1) s += __shfl_xor(s, sh, 64);
    __shared__ float red[4];
    if ((threadIdx.x & 63) == 0) red[threadIdx.x >> 6] = s;
    __syncthreads();
    if (threadIdx.x == 0) *out = red[0] + red[1] + red[2] + red[3];
}

// s_est = sqrt(||Xv||^2 / ||v||^2) <= sigma_max (Rayleigh); inv_s = 1/(1.06 s)
__global__ void rayleigh_kernel(const float* __restrict__ sy, const float* __restrict__ sv,
                                float* __restrict__ inv_s) {
    *inv_s = sqrtf(*sv / (*sy + 1e-30f)) * (1.0f / 1.06f);
}

// B0 = X * inv_s -> bf16 normal + bf16 transposed (tiled via LDS)
__global__ __launch_bounds__(256)
void scale_kernel(const float* __restrict__ Xf, const float* __restrict__ inv_s,
                  unsigned short* __restrict__ Bb, unsigned short* __restrict__ BTb)
{
    __shared__ unsigned short tile[64][65];
    const float is = *inv_s;
    const int bx = blockIdx.x * 64, by = blockIdx.y * 64;
    const int tx = threadIdx.x & 63, ty = threadIdx.x >> 6;
    for (int r = ty; r < 64; r += 4) {
        const float v = Xf[(size_t)(by + r) * N + bx + tx] * is;
        const unsigned short b = f2bf(v);
        Bb[(size_t)(by + r) * N + bx + tx] = b;
        tile[r][tx] = b;
    }
    __syncthreads();
    for (int r = ty; r < 64; r += 4)
        BTb[(size_t)(bx + r) * N + by + tx] = tile[tx][r];
}

// Re-center B_next = P * Bn * P using its row/col/total sums.
// FINAL=0: emit bf16 B + bf16 B^T for the next step.
// FINAL=1: emit H = centered + 1/n (fp32, in place in d_out).
template<int FINAL>
__global__ __launch_bounds__(256)
void center_kernel(float* __restrict__ Bn, const float* __restrict__ rowsum,
                   const float* __restrict__ colsum, const float* __restrict__ tot,
                   unsigned short* __restrict__ Bb, unsigned short* __restrict__ BTb)
{
    __shared__ unsigned short tile[64][65];
    constexpr float invn = 1.0f / N;
    const float tm = *tot * invn * invn;
    const int bx = blockIdx.x * 64, by = blockIdx.y * 64;
    const int tx = threadIdx.x & 63, ty = threadIdx.x >> 6;
    for (int r = ty; r < 64; r += 4) {
        const size_t idx = (size_t)(by + r) * N + bx + tx;
        const float v = Bn[idx] - rowsum[by + r] * invn - colsum[bx + tx] * invn + tm;
        if constexpr (FINAL) {
            Bn[idx] = v + invn;   // + e0 e0^T (entries 1/n)
        } else {
            const unsigned short b = f2bf(v);
            Bb[idx] = b;
            tile[r][tx] = b;
        }
    }
    if constexpr (!FINAL) {
        __syncthreads();
        for (int r = ty; r < 64; r += 4)
            BTb[(size_t)(bx + r) * N + by + tx] = tile[tx][r];
    }
}

// ---------------------------------------------------------------------------
extern "C" void kernel_launch(void* const* d_in, const int* in_sizes, int n_in,
                              void* d_out, int out_size, void* d_ws, size_t ws_size,
                              hipStream_t stream)
{
    const float* H_raw = (const float*)d_in[0];   // 2048x2048 fp32; d_in[1] (U) unused
    float* F32A = (float*)d_out;                  // fp32 staging + final H

    char* ws = (char*)d_ws;                       // ~25.3 MB used
    unsigned short* Bb  = (unsigned short*)(ws);
    unsigned short* BTb = (unsigned short*)(ws + 8388608);
    unsigned short* Mb  = (unsigned short*)(ws + 16777216);
    float* base   = (float*)(ws + 25165824);
    float* rowsum = base;             // N
    float* colsum = base + 2048;      // N
    float* total  = base + 4096;
    float* sumsq_y = base + 4097;
    float* sumsq_v = base + 4098;
    float* inv_s   = base + 4099;
    float* va = base + 4100;          // N (16B-aligned: 4100*4 % 16 == 0)
    float* vb = base + 6148;          // N
    float* yv = base + 8196;          // N

    const dim3 gt(32, 32);            // 64x64 tile kernels

    hipMemsetAsync(rowsum, 0, (size_t)(2 * N + 3) * sizeof(float), stream);

    // ---- projection: X = P H P ----
    rowsum_kernel<<<N, 256, 0, stream>>>(H_raw, rowsum);
    colsum_kernel<<<dim3(8, 32), 256, 0, stream>>>(H_raw, colsum);
    total_kernel<<<1, 256, 0, stream>>>(rowsum, total);
    project_kernel<<<4096, 256, 0, stream>>>(H_raw, rowsum, colsum, total, F32A, Bb);

    // ---- spectral-norm estimate: 4 Gram power iterations + Rayleigh ----
    init_v<<<8, 256, 0, stream>>>(va);
    float *pa = va, *pb = vb;
    for (int it = 0; it < 4; ++it) {
        matvec_row<<<256, 256, 0, stream>>>(Bb, pa, yv);
        hipMemsetAsync(pb, 0, N * sizeof(float), stream);
        matvec_colT<<<dim3(8, 32), 256, 0, stream>>>(Bb, yv, pb);
        float* t = pa; pa = pb; pb = t;
    }
    sumsq_kernel<<<1, 256, 0, stream>>>(pa, sumsq_v);
    matvec_row<<<256, 256, 0, stream>>>(Bb, pa, yv);
    sumsq_kernel<<<1, 256, 0, stream>>>(yv, sumsq_y);
    rayleigh_kernel<<<1, 1, 0, stream>>>(sumsq_y, sumsq_v, inv_s);
    scale_kernel<<<gt, 256, 0, stream>>>(F32A, inv_s, Bb, BTb);   // B0 = X/s (bf16 + bf16^T)

    // ---- Newton-Schulz: B <- (1.5I - 0.5 B B^T) B, re-centered each step ----
    for (int step = 0; step < NSTEPS; ++step) {
        gemm_bt<1><<<512, 256, 0, stream>>>(Bb, Bb, Mb, nullptr, nullptr, nullptr, nullptr);
        hipMemsetAsync(rowsum, 0, (size_t)(2 * N + 1) * sizeof(float), stream);
        gemm_bt<2><<<512, 256, 0, stream>>>(Mb, BTb, nullptr, F32A, rowsum, colsum, total);
        if (step < NSTEPS - 1)
            center_kernel<0><<<gt, 256, 0, stream>>>(F32A, rowsum, colsum, total, Bb, BTb);
        else
            center_kernel<1><<<gt, 256, 0, stream>>>(F32A, rowsum, colsum, total, nullptr, nullptr);
    }
}

// Round 4
// 509.403 us; speedup vs baseline: 1.9753x; 1.1363x over previous
//
#include <hip/hip_runtime.h>
#include <hip/hip_bf16.h>
#include <cstdint>

// ============================================================================
// IsoNSProject: H = e0 e0^T + polar(P H_raw P) restricted to 1-perp subspace.
// NS iteration conjugated into n-dim space (U never materialized):
//   B0 = P H P / s,  B <- (1.5 I - 0.5 B B^T) B,  H = B_final + 1/n.
// Spectral norm s via 4 Gram power iterations + Rayleigh quotient (x1.06).
// GEMM: 128x128 tile, BK=64, double-buffered global_load_lds (64 KB LDS),
// SPLIT-K=2 inside one dispatch: 256 tiles x 2 k-slices = 512 blocks =
// 2 blocks/CU; the two resident blocks stream DIFFERENT k-slabs (de-phased).
// fp32 partials -> two buffers (no atomics); consumers sum the pair.
// NSTEPS=4: worst-case sigma0 ~0.63 -> residual ~1.2e-5 < bf16 noise floor.
// ============================================================================

#define N 2048
#define NSTEPS 4

typedef __bf16 bf16x8 __attribute__((ext_vector_type(8)));
typedef float  f32x4  __attribute__((ext_vector_type(4)));

typedef const void __attribute__((address_space(1))) gvoid;
typedef void __attribute__((address_space(3)))       svoid;

__device__ __forceinline__ void load16_lds(const void* g, void* l) {
    // 16B direct global->LDS DMA; LDS dest = wave-uniform base + lane*16.
    __builtin_amdgcn_global_load_lds((gvoid*)(uintptr_t)g,
                                     (svoid*)(uint32_t)(uintptr_t)l, 16, 0, 0);
}

__device__ __forceinline__ unsigned short f2bf(float x) {
    __hip_bfloat16 h = __float2bfloat16(x);   // RNE
    return *reinterpret_cast<unsigned short*>(&h);
}
__device__ __forceinline__ float u2f(unsigned u) { float f; __builtin_memcpy(&f, &u, 4); return f; }
__device__ __forceinline__ float bflo(unsigned u) { return u2f(u << 16); }
__device__ __forceinline__ float bfhi(unsigned u) { return u2f(u & 0xFFFF0000u); }
__device__ __forceinline__ float b2f(unsigned short b) { return u2f(((unsigned)b) << 16); }

// ---------------------------------------------------------------------------
// GEMM partial: C_ks = A * B^T over K-slice ks (both operands [row][k]).
// 512 blocks: tile t = id>>1 (16x16 grid of 128x128), k-slice ks = id&1
// (K in [ks*1024, ks*1024+1024)). 4 waves, 2x2 of 64x64 wave tiles, BK=64.
// LDS 16B-slot layout swizzled: slot(r,c) = r*8 + (c ^ (r&7)); DMA lane layout
// is fixed (base + lane*16) so the swizzle is applied to the global SOURCE
// address. Frag ds_read_b128 then hit 2 lanes/bank (free).
// MODE 1: Cf = acc (fp32 partial)                      (S = B B^T)
// MODE 2: Cf = acc (fp32 partial) + row/col/tot atomics (linear over slices)
// ---------------------------------------------------------------------------
template<int MODE>
__global__ __launch_bounds__(256, 2)
void gemm_bt(const unsigned short* __restrict__ A, const unsigned short* __restrict__ B,
             float* __restrict__ C0, float* __restrict__ C1,
             float* __restrict__ rowsum, float* __restrict__ colsum,
             float* __restrict__ tot)
{
    __shared__ __align__(16) unsigned short As[2][128 * 64];  // 16 KB / buffer
    __shared__ __align__(16) unsigned short Bs[2][128 * 64];

    const int tid  = threadIdx.x;
    const int wave = tid >> 6;
    const int lane = tid & 63;

    const int id = blockIdx.x;
    const int t  = id >> 1;          // tile 0..255
    const int ks = id & 1;           // k-slice
    const int bm = (t >> 4) * 128;
    const int bn = (t & 15) * 128;
    const int kbase = ks * (N / 2);
    float* __restrict__ Cf = ks ? C1 : C0;

    const int wm = (wave >> 1) * 64;
    const int wn = (wave & 1) * 64;
    const int lr = lane & 15;   // row-in-16 for frags / col for C
    const int q  = lane >> 4;   // k-quad for frags / row-quad for C
    const int l7 = lr & 7;

    f32x4 acc[4][4] = {};

    // Stage one BK=64 slab of both 128-row tiles (16 KB each = 4 DMAs/wave).
    auto stage = [&](int buf, int k0) {
        #pragma unroll
        for (int j = 0; j < 4; ++j) {
            const int s0 = (wave * 4 + j) * 64;                 // slot base
            const int rr = (s0 >> 3) + (lane >> 3);             // row 0..127
            const int cc = (lane & 7) ^ ((lane >> 3) & 7);      // k-chunk
            const size_t go = (size_t)k0 + cc * 8;
            load16_lds(A + (size_t)(bm + rr) * N + go, (void*)&As[buf][s0 * 8]);
            load16_lds(B + (size_t)(bn + rr) * N + go, (void*)&Bs[buf][s0 * 8]);
        }
    };

    stage(0, kbase);
    constexpr int KT = (N / 2) / 64;   // 16
    for (int kt = 0; kt < KT; ++kt) {
        const int cur = kt & 1;
        __syncthreads();   // vmcnt(0) drain: buf[cur]'s DMA (issued last iter) lands
        if (kt + 1 < KT) stage(cur ^ 1, kbase + (kt + 1) * 64);

        bf16x8 af[2][4], bfr[2][4];
        #pragma unroll
        for (int kk = 0; kk < 2; ++kk) {
            const int cs = (kk * 4 + q) ^ l7;
            #pragma unroll
            for (int mi = 0; mi < 4; ++mi) {
                af [kk][mi] = *(const bf16x8*)&As[cur][((wm + mi * 16 + lr) * 8 + cs) * 8];
                bfr[kk][mi] = *(const bf16x8*)&Bs[cur][((wn + mi * 16 + lr) * 8 + cs) * 8];
            }
        }
        #pragma unroll
        for (int kk = 0; kk < 2; ++kk)
            #pragma unroll
            for (int mi = 0; mi < 4; ++mi)
                #pragma unroll
                for (int nj = 0; nj < 4; ++nj)
                    acc[mi][nj] = __builtin_amdgcn_mfma_f32_16x16x32_bf16(af[kk][mi], bfr[kk][nj], acc[mi][nj], 0, 0, 0);
    }

    if constexpr (MODE == 1) {
        #pragma unroll
        for (int mi = 0; mi < 4; ++mi)
            #pragma unroll
            for (int nj = 0; nj < 4; ++nj)
                #pragma unroll
                for (int r = 0; r < 4; ++r) {
                    const int row = bm + wm + mi * 16 + q * 4 + r;  // C/D: row = quad*4+reg
                    const int col = bn + wn + nj * 16 + lr;         //      col = lane&15
                    Cf[(size_t)row * N + col] = acc[mi][nj][r];
                }
    } else {  // MODE 2: partial store + partial sums (linear over k-slices)
        float ltot = 0.f;
        #pragma unroll
        for (int mi = 0; mi < 4; ++mi) {
            #pragma unroll
            for (int r = 0; r < 4; ++r) {
                const int row = bm + wm + mi * 16 + q * 4 + r;
                float rs = 0.f;
                #pragma unroll
                for (int nj = 0; nj < 4; ++nj) {
                    const float v = acc[mi][nj][r];
                    Cf[(size_t)row * N + (bn + wn + nj * 16 + lr)] = v;
                    rs += v;
                }
                ltot += rs;
                rs += __shfl_xor(rs, 1, 64);
                rs += __shfl_xor(rs, 2, 64);
                rs += __shfl_xor(rs, 4, 64);
                rs += __shfl_xor(rs, 8, 64);
                if (lr == 0) atomicAdd(&rowsum[row], rs);
            }
        }
        #pragma unroll
        for (int nj = 0; nj < 4; ++nj) {
            float cs = 0.f;
            #pragma unroll
            for (int mi = 0; mi < 4; ++mi)
                #pragma unroll
                for (int r = 0; r < 4; ++r) cs += acc[mi][nj][r];
            cs += __shfl_xor(cs, 16, 64);
            cs += __shfl_xor(cs, 32, 64);
            if (q == 0) atomicAdd(&colsum[bn + wn + nj * 16 + lr], cs);
        }
        #pragma unroll
        for (int s = 1; s < 64; s <<= 1) ltot += __shfl_xor(ltot, s, 64);
        if (lane == 0) atomicAdd(tot, ltot);
    }
}

// M = bf16(1.5 I - 0.5 (C0 + C1))  (the NS "M" matrix, from fp32 partials)
__global__ __launch_bounds__(256)
void transform_kernel(const float* __restrict__ C0, const float* __restrict__ C1,
                      unsigned short* __restrict__ Mb)
{
    const size_t i4 = ((size_t)blockIdx.x * 256 + threadIdx.x) * 4;
    const int row = (int)(i4 >> 11);
    const int col = (int)(i4 & (N - 1));
    const float4 a = *(const float4*)(C0 + i4);
    const float4 b = *(const float4*)(C1 + i4);
    float v0 = (row == col + 0 ? 1.5f : 0.0f) - 0.5f * (a.x + b.x);
    float v1 = (row == col + 1 ? 1.5f : 0.0f) - 0.5f * (a.y + b.y);
    float v2 = (row == col + 2 ? 1.5f : 0.0f) - 0.5f * (a.z + b.z);
    float v3 = (row == col + 3 ? 1.5f : 0.0f) - 0.5f * (a.w + b.w);
    ushort4 o; o.x = f2bf(v0); o.y = f2bf(v1); o.z = f2bf(v2); o.w = f2bf(v3);
    *(ushort4*)(Mb + i4) = o;
}

// ---------------------------------------------------------------------------
// Small n^2 / n kernels
// ---------------------------------------------------------------------------
__global__ __launch_bounds__(256) void rowsum_kernel(const float* __restrict__ M, float* __restrict__ out) {
    const int row = blockIdx.x;
    float s = 0.f;
    for (int j = threadIdx.x; j < N; j += 256) s += M[(size_t)row * N + j];
    #pragma unroll
    for (int sh = 1; sh < 64; sh <<= 1) s += __shfl_xor(s, sh, 64);
    __shared__ float red[4];
    if ((threadIdx.x & 63) == 0) red[threadIdx.x >> 6] = s;
    __syncthreads();
    if (threadIdx.x == 0) out[row] = red[0] + red[1] + red[2] + red[3];
}

__global__ __launch_bounds__(256) void colsum_kernel(const float* __restrict__ M, float* __restrict__ out) {
    const int col = blockIdx.x * 256 + threadIdx.x;
    const int r0  = blockIdx.y * 64;
    float s = 0.f;
    for (int r = r0; r < r0 + 64; ++r) s += M[(size_t)r * N + col];
    atomicAdd(&out[col], s);
}

__global__ __launch_bounds__(256) void total_kernel(const float* __restrict__ rs, float* __restrict__ tot) {
    float s = 0.f;
    for (int i = threadIdx.x; i < N; i += 256) s += rs[i];
    #pragma unroll
    for (int sh = 1; sh < 64; sh <<= 1) s += __shfl_xor(s, sh, 64);
    __shared__ float red[4];
    if ((threadIdx.x & 63) == 0) red[threadIdx.x >> 6] = s;
    __syncthreads();
    if (threadIdx.x == 0) *tot = red[0] + red[1] + red[2] + red[3];
}

// X = P H P = H - rowmean_i - colmean_j + totalmean; write fp32 + bf16.
__global__ __launch_bounds__(256)
void project_kernel(const float* __restrict__ H, const float* __restrict__ rowsum,
                    const float* __restrict__ colsum, const float* __restrict__ tot,
                    float* __restrict__ Xf, unsigned short* __restrict__ Xb)
{
    constexpr float invn = 1.0f / N;
    const float tm = *tot * invn * invn;
    const size_t i4 = ((size_t)blockIdx.x * 256 + threadIdx.x) * 4;
    const int row = (int)(i4 >> 11);
    const int col = (int)(i4 & (N - 1));
    const float rm = rowsum[row] * invn;
    const float4 h = *(const float4*)(H + i4);
    float v0 = h.x - rm - colsum[col + 0] * invn + tm;
    float v1 = h.y - rm - colsum[col + 1] * invn + tm;
    float v2 = h.z - rm - colsum[col + 2] * invn + tm;
    float v3 = h.w - rm - colsum[col + 3] * invn + tm;
    *(float4*)(Xf + i4) = make_float4(v0, v1, v2, v3);
    ushort4 o; o.x = f2bf(v0); o.y = f2bf(v1); o.z = f2bf(v2); o.w = f2bf(v3);
    *(ushort4*)(Xb + i4) = o;
}

// ---- power iteration on the Gram matrix X^T X (X in bf16) ----
__global__ void init_v(float* __restrict__ v) {
    const int i = blockIdx.x * 256 + threadIdx.x;
    unsigned u = (unsigned)i * 2654435761u; u ^= u >> 16; u *= 2246822519u; u ^= u >> 13;
    v[i] = (float)(u & 0xFFFF) * (1.0f / 65536.0f) - 0.5f;
}

// y = X v  (row-wise dot; 8 rows/block, 32 lanes/row)
__global__ __launch_bounds__(256)
void matvec_row(const unsigned short* __restrict__ X, const float* __restrict__ v,
                float* __restrict__ y)
{
    const int r = blockIdx.x * 8 + (threadIdx.x >> 5);
    const int l = threadIdx.x & 31;
    const unsigned short* row = X + (size_t)r * N;
    float s = 0.f;
    #pragma unroll
    for (int kk = 0; kk < 8; ++kk) {
        const int c0 = kk * 256 + l * 8;
        const uint4  u  = *(const uint4*)(row + c0);
        const float4 va = *(const float4*)(v + c0);
        const float4 vb = *(const float4*)(v + c0 + 4);
        s += bflo(u.x) * va.x + bfhi(u.x) * va.y + bflo(u.y) * va.z + bfhi(u.y) * va.w
           + bflo(u.z) * vb.x + bfhi(u.z) * vb.y + bflo(u.w) * vb.z + bfhi(u.w) * vb.w;
    }
    #pragma unroll
    for (int sh = 1; sh < 32; sh <<= 1) s += __shfl_xor(s, sh, 64);
    if (l == 0) y[r] = s;
}

// vout += X^T y (vout pre-zeroed; 64-row strips, coalesced cols)
__global__ __launch_bounds__(256)
void matvec_colT(const unsigned short* __restrict__ X, const float* __restrict__ y,
                 float* __restrict__ vout)
{
    const int j  = blockIdx.x * 256 + threadIdx.x;
    const int r0 = blockIdx.y * 64;
    float s = 0.f;
    #pragma unroll 4
    for (int r = r0; r < r0 + 64; ++r) s += b2f(X[(size_t)r * N + j]) * y[r];
    atomicAdd(&vout[j], s);
}

__global__ __launch_bounds__(256) void sumsq_kernel(const float* __restrict__ x, float* __restrict__ out) {
    float s = 0.f;
    for (int i = threadIdx.x; i < N; i += 256) { const float v = x[i]; s += v * v; }
    #pragma unroll
    for (int sh = 1; sh < 64; sh <<= 1) s += __shfl_xor(s, sh, 64);
    __shared__ float red[4];
    if ((threadIdx.x & 63) == 0) red[threadIdx.x >> 6] = s;
    __syncthreads();
    if (threadIdx.x == 0) *out = red[0] + red[1] + red[2] + red[3];
}

// s_est = sqrt(||Xv||^2 / ||v||^2) <= sigma_max (Rayleigh); inv_s = 1/(1.06 s)
__global__ void rayleigh_kernel(const float* __restrict__ sy, const float* __restrict__ sv,
                                float* __restrict__ inv_s) {
    *inv_s = sqrtf(*sv / (*sy + 1e-30f)) * (1.0f / 1.06f);
}

// B0 = X * inv_s -> bf16 normal + bf16 transposed (tiled via LDS)
__global__ __launch_bounds__(256)
void scale_kernel(const float* __restrict__ Xf, const float* __restrict__ inv_s,
                  unsigned short* __restrict__ Bb, unsigned short* __restrict__ BTb)
{
    __shared__ unsigned short tile[64][65];
    const float is = *inv_s;
    const int bx = blockIdx.x * 64, by = blockIdx.y * 64;
    const int tx = threadIdx.x & 63, ty = threadIdx.x >> 6;
    for (int r = ty; r < 64; r += 4) {
        const float v = Xf[(size_t)(by + r) * N + bx + tx] * is;
        const unsigned short b = f2bf(v);
        Bb[(size_t)(by + r) * N + bx + tx] = b;
        tile[r][tx] = b;
    }
    __syncthreads();
    for (int r = ty; r < 64; r += 4)
        BTb[(size_t)(bx + r) * N + by + tx] = tile[tx][r];
}

// Re-center B_next = P (C0+C1) P using row/col/total sums.
// FINAL=0: emit bf16 B + bf16 B^T for the next step.
// FINAL=1: emit H = centered + 1/n (fp32, in place into C0 = d_out).
template<int FINAL>
__global__ __launch_bounds__(256)
void center_kernel(float* __restrict__ C0, const float* __restrict__ C1,
                   const float* __restrict__ rowsum, const float* __restrict__ colsum,
                   const float* __restrict__ tot,
                   unsigned short* __restrict__ Bb, unsigned short* __restrict__ BTb)
{
    __shared__ unsigned short tile[64][65];
    constexpr float invn = 1.0f / N;
    const float tm = *tot * invn * invn;
    const int bx = blockIdx.x * 64, by = blockIdx.y * 64;
    const int tx = threadIdx.x & 63, ty = threadIdx.x >> 6;
    for (int r = ty; r < 64; r += 4) {
        const size_t idx = (size_t)(by + r) * N + bx + tx;
        const float v = C0[idx] + C1[idx]
                      - rowsum[by + r] * invn - colsum[bx + tx] * invn + tm;
        if constexpr (FINAL) {
            C0[idx] = v + invn;   // + e0 e0^T (entries 1/n)
        } else {
            const unsigned short b = f2bf(v);
            Bb[idx] = b;
            tile[r][tx] = b;
        }
    }
    if constexpr (!FINAL) {
        __syncthreads();
        for (int r = ty; r < 64; r += 4)
            BTb[(size_t)(bx + r) * N + by + tx] = tile[tx][r];
    }
}

// ---------------------------------------------------------------------------
extern "C" void kernel_launch(void* const* d_in, const int* in_sizes, int n_in,
                              void* d_out, int out_size, void* d_ws, size_t ws_size,
                              hipStream_t stream)
{
    const float* H_raw = (const float*)d_in[0];   // 2048x2048 fp32; d_in[1] (U) unused
    float* C0 = (float*)d_out;                    // fp32 staging / partial 0 / final H

    char* ws = (char*)d_ws;                       // ~41.3 MB used
    unsigned short* Bb  = (unsigned short*)(ws);
    unsigned short* BTb = (unsigned short*)(ws + 8388608);
    unsigned short* Mb  = (unsigned short*)(ws + 16777216);
    float* C1     = (float*)(ws + 25165824);      // 16 MB fp32 partial 1
    float* base   = (float*)(ws + 41943040);
    float* rowsum = base;             // N
    float* colsum = base + 2048;      // N
    float* total  = base + 4096;
    float* sumsq_y = base + 4097;
    float* sumsq_v = base + 4098;
    float* inv_s   = base + 4099;
    float* va = base + 4100;          // N (16B-aligned)
    float* vb = base + 6148;          // N
    float* yv = base + 8196;          // N

    const dim3 gt(32, 32);            // 64x64 tile kernels

    hipMemsetAsync(rowsum, 0, (size_t)(2 * N + 3) * sizeof(float), stream);

    // ---- projection: X = P H P ----
    rowsum_kernel<<<N, 256, 0, stream>>>(H_raw, rowsum);
    colsum_kernel<<<dim3(8, 32), 256, 0, stream>>>(H_raw, colsum);
    total_kernel<<<1, 256, 0, stream>>>(rowsum, total);
    project_kernel<<<4096, 256, 0, stream>>>(H_raw, rowsum, colsum, total, C0, Bb);

    // ---- spectral-norm estimate: 4 Gram power iterations + Rayleigh ----
    init_v<<<8, 256, 0, stream>>>(va);
    float *pa = va, *pb = vb;
    for (int it = 0; it < 4; ++it) {
        matvec_row<<<256, 256, 0, stream>>>(Bb, pa, yv);
        hipMemsetAsync(pb, 0, N * sizeof(float), stream);
        matvec_colT<<<dim3(8, 32), 256, 0, stream>>>(Bb, yv, pb);
        float* t = pa; pa = pb; pb = t;
    }
    sumsq_kernel<<<1, 256, 0, stream>>>(pa, sumsq_v);
    matvec_row<<<256, 256, 0, stream>>>(Bb, pa, yv);
    sumsq_kernel<<<1, 256, 0, stream>>>(yv, sumsq_y);
    rayleigh_kernel<<<1, 1, 0, stream>>>(sumsq_y, sumsq_v, inv_s);
    scale_kernel<<<gt, 256, 0, stream>>>(C0, inv_s, Bb, BTb);   // B0 = X/s (bf16 + bf16^T)

    // ---- Newton-Schulz: B <- (1.5I - 0.5 B B^T) B, re-centered each step ----
    for (int step = 0; step < NSTEPS; ++step) {
        // S partials (C0 free: X consumed by scale / prev Bn consumed by center)
        gemm_bt<1><<<512, 256, 0, stream>>>(Bb, Bb, C0, C1, nullptr, nullptr, nullptr);
        transform_kernel<<<4096, 256, 0, stream>>>(C0, C1, Mb);
        hipMemsetAsync(rowsum, 0, (size_t)(2 * N + 1) * sizeof(float), stream);
        // Bn partials + linear row/col/tot sums
        gemm_bt<2><<<512, 256, 0, stream>>>(Mb, BTb, C0, C1, rowsum, colsum, total);
        if (step < NSTEPS - 1)
            center_kernel<0><<<gt, 256, 0, stream>>>(C0, C1, rowsum, colsum, total, Bb, BTb);
        else
            center_kernel<1><<<gt, 256, 0, stream>>>(C0, C1, rowsum, colsum, total, nullptr, nullptr);
    }
}